// Round 16
// baseline (123.924 us; speedup 1.0000x reference)
//
#include <hip/hip_runtime.h>
#include <hip/hip_bf16.h>
#include <math.h>

// Problem constants
#define Bc 8
#define Nc 512
#define Tc 64
#define Cc 128
#define Mc 32
#define MEMc 20
#define Ec 4

// LDS strides (bf16 elements)
#define LDK  40   // sh_k  [64][40]
#define LDVT 72   // sh_vt [32][72]

typedef short bf16x8 __attribute__((ext_vector_type(8)));
typedef float f32x4  __attribute__((ext_vector_type(4)));

__device__ __forceinline__ unsigned short f2bfu(float f) {
    return __builtin_bit_cast(unsigned short, __float2bfloat16(f));
}
__device__ __forceinline__ unsigned pk2bf(float x, float y) {
    return ((unsigned)f2bfu(y) << 16) | (unsigned)f2bfu(x);
}

// global->LDS direct DMA, 16 B per lane (dest = uniform base + lane*16)
__device__ __forceinline__ void gload_lds16(const void* g, void* l) {
    __builtin_amdgcn_global_load_lds(
        (const __attribute__((address_space(1))) unsigned int*)g,
        (__attribute__((address_space(3))) unsigned int*)l, 16, 0, 0);
}

// ---- prep (blocks 0..191): swizzled bf16 weight image wt_img[e][mat][m][c ^ ((m&7)<<3)]
//      block 192: bankM[m][k] bf16 (K zero-padded to 32) + G2[k][2] = iq @ membank^T.
__global__ void prep(const float* __restrict__ Wq, const float* __restrict__ Wk,
                     const float* __restrict__ Wv, const float* __restrict__ membank,
                     const float* __restrict__ iq,
                     short* __restrict__ wt_img, short* __restrict__ bankM,
                     float* __restrict__ G2) {
    const int t = threadIdx.x;
    if (blockIdx.x < 192) {
        int idx = blockIdx.x * 256 + t;                 // 49152 = 4*3*32*128
        int e   = idx / 12288;
        int r   = idx - e * 12288;
        int mat = r >> 12;
        int m   = (r >> 7) & 31;
        int c   = r & 127;
        const float* W = (mat == 0) ? Wq : (mat == 1) ? Wk : Wv;
        const int dst = e * 12288 + mat * 4096 + m * 128 + (c ^ ((m & 7) << 3));
        wt_img[dst] = (short)f2bfu(W[((size_t)e * Cc + c) * Mc + m]);
    } else {
        for (int idx = t; idx < Mc * 32; idx += 256) {
            int m = idx >> 5, k = idx & 31;
            bankM[idx] = (short)f2bfu((k < MEMc) ? membank[k * Mc + m] : 0.f);
        }
        if (t < MEMc) {
            float g0 = 0.f, g1 = 0.f;
            for (int m = 0; m < Mc; ++m) {
                float b = membank[t * Mc + m];
                g0 = fmaf(iq[m], b, g0);
                g1 = fmaf(iq[Mc + m], b, g1);
            }
            G2[2 * t]     = g0;
            G2[2 * t + 1] = g1;
        }
    }
}

// ---- projection for one unit: q/k/v^T = W^T @ H^T (B-frags from swizzled sh_wt)
__device__ __forceinline__ void proj(const short* __restrict__ sh_wt, const bf16x8* a,
                                     int lo, int hi,
                                     f32x4 q_[2], f32x4 k_[2], f32x4 v_[2]) {
    #pragma unroll
    for (int nt = 0; nt < 2; ++nt)
        q_[nt] = k_[nt] = v_[nt] = (f32x4){0.f, 0.f, 0.f, 0.f};
    const int swz = (lo & 7) << 3;
    int col[4];
    #pragma unroll
    for (int kt = 0; kt < 4; ++kt) col[kt] = (kt * 32 + hi * 8) ^ swz;
    const short* wrow = sh_wt + lo * 128;
    __builtin_amdgcn_s_setprio(1);   // T5: prefer this wave through the MFMA-dense cluster
    #pragma unroll
    for (int nt = 0; nt < 2; ++nt) {
        const short* p0 = wrow + nt * 2048;
        #pragma unroll
        for (int kt = 0; kt < 4; ++kt) {
            const bf16x8 wq = *(const bf16x8*)(p0 + col[kt]);
            const bf16x8 wk = *(const bf16x8*)(p0 + 4096 + col[kt]);
            const bf16x8 wv = *(const bf16x8*)(p0 + 8192 + col[kt]);
            q_[nt] = __builtin_amdgcn_mfma_f32_16x16x32_bf16(wq, a[kt], q_[nt], 0, 0, 0);
            k_[nt] = __builtin_amdgcn_mfma_f32_16x16x32_bf16(wk, a[kt], k_[nt], 0, 0, 0);
            v_[nt] = __builtin_amdgcn_mfma_f32_16x16x32_bf16(wv, a[kt], v_[nt], 0, 0, 0);
        }
    }
    __builtin_amdgcn_s_setprio(0);
}

// ---- mem-gate exps (packed bf16 pairs), unnormalized (1/l cancels in cosine)
__device__ __forceinline__ void gate_pd(const float* __restrict__ G2, float2 in2, unsigned pd[10]) {
    #pragma unroll
    for (int kp = 0; kp < 10; ++kp) {
        const float4 g = *(const float4*)(G2 + 4 * kp);
        pd[kp] = pk2bf(__expf(in2.x * g.x + in2.y * g.y),
                       __expf(in2.x * g.z + in2.y * g.w));
    }
}

// ---- memories^T = bank^T @ P2^T (reg-only bpermute B-frag)
__device__ __forceinline__ void mem_read(const short* __restrict__ bankM,
                                         const unsigned pd[10], int lo, int hi, int w,
                                         f32x4 am[2]) {
    am[0] = am[1] = (f32x4){0.f, 0.f, 0.f, 0.f};
    const int addrD = (w * 16 + lo) * 4;
    unsigned Wd[10];
    #pragma unroll
    for (int u = 0; u < 10; ++u)
        Wd[u] = __builtin_amdgcn_ds_bpermute(addrD, (int)pd[u]);
    unsigned b[4];
    #pragma unroll
    for (int u = 0; u < 4; ++u) {
        const unsigned l_ = (hi == 0) ? Wd[u] : Wd[4 + u];
        const unsigned h_ = (u < 2) ? ((hi == 2) ? Wd[8 + u] : 0u) : 0u;
        b[u] = (hi < 2) ? l_ : h_;
    }
    const bf16x8 bp2 = __builtin_bit_cast(bf16x8, (uint4){b[0], b[1], b[2], b[3]});
    #pragma unroll
    for (int nt = 0; nt < 2; ++nt) {
        const bf16x8 ab = *(const bf16x8*)(bankM + (nt * 16 + lo) * 32 + hi * 8);
        am[nt] = __builtin_amdgcn_mfma_f32_16x16x32_bf16(ab, bp2, am[nt], 0, 0, 0);
    }
}

// ---- E + F + cosine + store for one unit
__device__ __forceinline__ void attend_store(
    const short* __restrict__ shk, const short* __restrict__ shv,
    const unsigned q_pk[4], const f32x4 am[2],
    int lo, int hi, int w, int A01, int A23, int addrA, int addrB,
    int bn, int e, float* __restrict__ out) {
    // E: energy^T = K @ Q^T; Q B-frag via bpermute; no max-subtraction
    unsigned pw[4][2];
    {
        unsigned l0 = __builtin_amdgcn_ds_bpermute(A01, (int)q_pk[0]);
        unsigned h0_ = __builtin_amdgcn_ds_bpermute(A01, (int)q_pk[2]);
        unsigned l1 = __builtin_amdgcn_ds_bpermute(A01, (int)q_pk[1]);
        unsigned h1_ = __builtin_amdgcn_ds_bpermute(A01, (int)q_pk[3]);
        unsigned l2 = __builtin_amdgcn_ds_bpermute(A23, (int)q_pk[0]);
        unsigned h2_ = __builtin_amdgcn_ds_bpermute(A23, (int)q_pk[2]);
        unsigned l3 = __builtin_amdgcn_ds_bpermute(A23, (int)q_pk[1]);
        unsigned h3_ = __builtin_amdgcn_ds_bpermute(A23, (int)q_pk[3]);
        const bf16x8 bq = __builtin_bit_cast(bf16x8, (uint4){
            (hi < 2) ? l0 : h0_, (hi < 2) ? l1 : h1_,
            (hi < 2) ? l2 : h2_, (hi < 2) ? l3 : h3_});
        __builtin_amdgcn_s_setprio(1);   // T5: E-cluster (4 MFMA + exp)
        #pragma unroll
        for (int st = 0; st < 4; ++st) {
            const bf16x8 akf = *(const bf16x8*)&shk[(st * 16 + lo) * LDK + hi * 8];
            const f32x4 en = __builtin_amdgcn_mfma_f32_16x16x32_bf16(
                akf, bq, (f32x4){0.f, 0.f, 0.f, 0.f}, 0, 0, 0);
            pw[st][0] = pk2bf(__expf(en[0]), __expf(en[1]));
            pw[st][1] = pk2bf(__expf(en[2]), __expf(en[3]));
        }
        __builtin_amdgcn_s_setprio(0);
    }
    // F: att^T = V^T @ P^T; P B-frag from pw via bpermute
    f32x4 av[2];
    av[0] = av[1] = (f32x4){0.f, 0.f, 0.f, 0.f};
    {
        bf16x8 bp[2];
        #pragma unroll
        for (int kt = 0; kt < 2; ++kt) {
            unsigned wrd[4];
            #pragma unroll
            for (int uu = 0; uu < 4; ++uu) {
                const int adr = (uu < 2) ? addrA : addrB;
                const unsigned ev = __builtin_amdgcn_ds_bpermute(adr, (int)pw[2 * kt][uu & 1]);
                const unsigned od = __builtin_amdgcn_ds_bpermute(adr, (int)pw[2 * kt + 1][uu & 1]);
                wrd[uu] = (hi < 2) ? ev : od;
            }
            bp[kt] = __builtin_bit_cast(bf16x8, (uint4){wrd[0], wrd[1], wrd[2], wrd[3]});
        }
        __builtin_amdgcn_s_setprio(1);   // T5: F-cluster (4 MFMA)
        #pragma unroll
        for (int nt = 0; nt < 2; ++nt)
            #pragma unroll
            for (int kt = 0; kt < 2; ++kt) {
                const bf16x8 avt = *(const bf16x8*)&shv[(nt * 16 + lo) * LDVT + kt * 32 + hi * 8];
                av[nt] = __builtin_amdgcn_mfma_f32_16x16x32_bf16(avt, bp[kt], av[nt], 0, 0, 0);
            }
        __builtin_amdgcn_s_setprio(0);
    }
    // cosine vs in-register memories^T, store
    float d = 0.f, na = 0.f, nb = 0.f;
    #pragma unroll
    for (int nt = 0; nt < 2; ++nt)
        #pragma unroll
        for (int j = 0; j < 4; ++j) {
            const float av_ = av[nt][j], am_ = am[nt][j];
            d  = fmaf(av_, am_, d);
            na = fmaf(av_, av_, na);
            nb = fmaf(am_, am_, nb);
        }
    d  += __shfl_xor(d, 16);  d  += __shfl_xor(d, 32);
    na += __shfl_xor(na, 16); na += __shfl_xor(na, 32);
    nb += __shfl_xor(nb, 16); nb += __shfl_xor(nb, 32);
    if (hi == 0) {
        const float denom = fmaxf(sqrtf(na), 1e-8f) * fmaxf(sqrtf(nb), 1e-8f);
        out[((size_t)bn * Tc + w * 16 + lo) * Ec + e] = d / denom;
    }
}

__global__ __launch_bounds__(256, 4) void mg_mfma(
    const float* __restrict__ input,    // [B,N,T,2]
    const float* __restrict__ hidden,   // [E,B,N,T,C]
    const short* __restrict__ wt_img,   // [E][3][32][128] bf16, row-swizzled
    const short* __restrict__ bankM,    // [32][32] bf16 (memory^T, K zero-padded)
    const float* __restrict__ G2,       // [20][2] fp32
    float* __restrict__ out)            // [B,N,T,1,E]
{
    __shared__ __align__(16) short sh_wt[12288];      // 24576 B
    __shared__ __align__(16) short sh_k [Tc * LDK];   //  5120 B (single buffer)
    __shared__ __align__(16) short sh_vt[Mc * LDVT];  //  4608 B -> 34304 B, 4 blocks/CU

    const int t    = threadIdx.x;
    const int w    = t >> 6;
    const int lane = t & 63;
    const int lo   = lane & 15;
    const int hi   = lane >> 4;
    const int e    = blockIdx.x >> 11;
    const int bn0  = (blockIdx.x & 2047) * 2;
    const int bn1  = bn0 + 1;

    const int A01   = (((hi & 1) * 32) + lo) << 2;
    const int A23   = A01 + 64;
    const int addrA = (((hi & 1) * 2 + 0) * 16 + lo) * 4;
    const int addrB = (((hi & 1) * 2 + 1) * 16 + lo) * 4;

    // ---- A0: weight-slice DMA to LDS (6 x 4KB linear; image pre-swizzled)
    {
        const short* gsrc = wt_img + (size_t)e * 12288 + w * 512 + lane * 8;
        short* ldst = sh_wt + w * 512;
        #pragma unroll
        for (int c = 0; c < 6; ++c)
            gload_lds16(gsrc + c * 2048, ldst + c * 2048);
    }

    // ---- A1: unit-0 hidden loads + both units' input
    const float2 in2_0 = *(const float2*)(input + ((size_t)bn0 * Tc + lane) * 2);
    const float2 in2_1 = *(const float2*)(input + ((size_t)bn1 * Tc + lane) * 2);
    float4 h[8];
    {
        const float* hr0 = hidden + (((size_t)(e * 4096 + bn0)) * Tc + w * 16 + lo) * Cc + hi * 8;
        #pragma unroll
        for (int kt = 0; kt < 4; ++kt) {
            h[2 * kt]     = *(const float4*)(hr0 + kt * 32);
            h[2 * kt + 1] = *(const float4*)(hr0 + kt * 32 + 4);
        }
    }

    // ---- B0 + D0 in the load shadow
    f32x4 am0[2];
    {
        unsigned pd0[10];
        gate_pd(G2, in2_0, pd0);
        mem_read(bankM, pd0, lo, hi, w, am0);
    }

    // ---- convert unit-0 A-frags (drains h0)
    bf16x8 a0[4];
    #pragma unroll
    for (int kt = 0; kt < 4; ++kt) {
        const float4 x = h[2 * kt], y = h[2 * kt + 1];
        a0[kt] = __builtin_bit_cast(bf16x8, (uint4){pk2bf(x.x, x.y), pk2bf(x.z, x.w),
                                                    pk2bf(y.x, y.y), pk2bf(y.z, y.w)});
    }

    __syncthreads();   // #1: sh_wt visible (drains weight DMA)

    // ---- C(0): projections, write K0/V0 to LDS, pack Q0
    unsigned q_pk0[4];
    {
        f32x4 q_[2], k_[2], v_[2];
        proj(sh_wt, a0, lo, hi, q_, k_, v_);
        #pragma unroll
        for (int nt = 0; nt < 2; ++nt) {
            *(uint2*)&sh_k[(w * 16 + lo) * LDK + nt * 16 + hi * 4] =
                (uint2){pk2bf(k_[nt][0], k_[nt][1]), pk2bf(k_[nt][2], k_[nt][3])};
            #pragma unroll
            for (int j = 0; j < 4; ++j)
                sh_vt[(nt * 16 + hi * 4 + j) * LDVT + w * 16 + lo] = (short)f2bfu(v_[nt][j]);
            q_pk0[nt * 2]     = pk2bf(q_[nt][0], q_[nt][1]);
            q_pk0[nt * 2 + 1] = pk2bf(q_[nt][2], q_[nt][3]);
        }
    }

    __syncthreads();   // #2: K0/V0 ready

    // ---- issue unit-1 hidden loads NOW (fly under E+F(0) and B1/D1)
    {
        const float* hr1 = hidden + (((size_t)(e * 4096 + bn1)) * Tc + w * 16 + lo) * Cc + hi * 8;
        #pragma unroll
        for (int kt = 0; kt < 4; ++kt) {
            h[2 * kt]     = *(const float4*)(hr1 + kt * 32);
            h[2 * kt + 1] = *(const float4*)(hr1 + kt * 32 + 4);
        }
    }

    // ---- B1 + D1 (VALU/DS work in the unit-1 load shadow)
    f32x4 am1[2];
    {
        unsigned pd1[10];
        gate_pd(G2, in2_1, pd1);
        mem_read(bankM, pd1, lo, hi, w, am1);
    }

    // ---- E+F(0) + store
    attend_store(sh_k, sh_vt, q_pk0, am0, lo, hi, w, A01, A23, addrA, addrB, bn0, e, out);

    // ---- convert unit-1 A-frags (drains h1; by now latency is covered)
    bf16x8 a1[4];
    #pragma unroll
    for (int kt = 0; kt < 4; ++kt) {
        const float4 x = h[2 * kt], y = h[2 * kt + 1];
        a1[kt] = __builtin_bit_cast(bf16x8, (uint4){pk2bf(x.x, x.y), pk2bf(x.z, x.w),
                                                    pk2bf(y.x, y.y), pk2bf(y.z, y.w)});
    }

    __syncthreads();   // #3: WAR — all waves done reading K0/V0

    // ---- C(1): projections, write K1/V1 to the SAME buffers, pack Q1
    unsigned q_pk1[4];
    {
        f32x4 q_[2], k_[2], v_[2];
        proj(sh_wt, a1, lo, hi, q_, k_, v_);
        #pragma unroll
        for (int nt = 0; nt < 2; ++nt) {
            *(uint2*)&sh_k[(w * 16 + lo) * LDK + nt * 16 + hi * 4] =
                (uint2){pk2bf(k_[nt][0], k_[nt][1]), pk2bf(k_[nt][2], k_[nt][3])};
            #pragma unroll
            for (int j = 0; j < 4; ++j)
                sh_vt[(nt * 16 + hi * 4 + j) * LDVT + w * 16 + lo] = (short)f2bfu(v_[nt][j]);
            q_pk1[nt * 2]     = pk2bf(q_[nt][0], q_[nt][1]);
            q_pk1[nt * 2 + 1] = pk2bf(q_[nt][2], q_[nt][3]);
        }
    }

    __syncthreads();   // #4: K1/V1 ready

    // ---- E+F(1) + store
    attend_store(sh_k, sh_vt, q_pk1, am1, lo, hi, w, A01, A23, addrA, addrB, bn1, e, out);
}

extern "C" void kernel_launch(void* const* d_in, const int* in_sizes, int n_in,
                              void* d_out, int out_size, void* d_ws, size_t ws_size,
                              hipStream_t stream) {
    const float* input   = (const float*)d_in[0];
    const float* hidden  = (const float*)d_in[1];
    const float* membank = (const float*)d_in[2];
    const float* iq      = (const float*)d_in[3];
    const float* Wq      = (const float*)d_in[4];
    const float* Wk      = (const float*)d_in[5];
    const float* Wv      = (const float*)d_in[6];
    float* out = (float*)d_out;

    short* wt_img = (short*)d_ws;                      // 98304 B
    short* bankM  = (short*)((char*)d_ws + 98304);     //  2048 B
    float* G2     = (float*)((char*)d_ws + 100352);    //   160 B

    prep<<<193, 256, 0, stream>>>(Wq, Wk, Wv, membank, iq, wt_img, bankM, G2);
    mg_mfma<<<Ec * Bc * Nc / 2, 256, 0, stream>>>(input, hidden, wt_img, bankM, G2, out);
}

// Round 17
// 119.431 us; speedup vs baseline: 1.0376x; 1.0376x over previous
//
#include <hip/hip_runtime.h>
#include <hip/hip_bf16.h>
#include <math.h>

// Problem constants
#define Bc 8
#define Nc 512
#define Tc 64
#define Cc 128
#define Mc 32
#define MEMc 20
#define Ec 4

// LDS strides (bf16 elements)
#define LDK  40   // sh_k  [64][40]
#define LDVT 72   // sh_vt [32][72]

typedef short bf16x8 __attribute__((ext_vector_type(8)));
typedef float f32x4  __attribute__((ext_vector_type(4)));

__device__ __forceinline__ unsigned short f2bfu(float f) {
    return __builtin_bit_cast(unsigned short, __float2bfloat16(f));
}
__device__ __forceinline__ unsigned pk2bf(float x, float y) {
    return ((unsigned)f2bfu(y) << 16) | (unsigned)f2bfu(x);
}

// global->LDS direct DMA, 16 B per lane (dest = uniform base + lane*16)
__device__ __forceinline__ void gload_lds16(const void* g, void* l) {
    __builtin_amdgcn_global_load_lds(
        (const __attribute__((address_space(1))) unsigned int*)g,
        (__attribute__((address_space(3))) unsigned int*)l, 16, 0, 0);
}

// ---- prep (blocks 0..191): swizzled bf16 weight image wt_img[e][mat][m][c ^ ((m&7)<<3)]
//      block 192: bankM[m][k] bf16 (K zero-padded to 32) + G2[k][2] = iq @ membank^T.
__global__ void prep(const float* __restrict__ Wq, const float* __restrict__ Wk,
                     const float* __restrict__ Wv, const float* __restrict__ membank,
                     const float* __restrict__ iq,
                     short* __restrict__ wt_img, short* __restrict__ bankM,
                     float* __restrict__ G2) {
    const int t = threadIdx.x;
    if (blockIdx.x < 192) {
        int idx = blockIdx.x * 256 + t;                 // 49152 = 4*3*32*128
        int e   = idx / 12288;
        int r   = idx - e * 12288;
        int mat = r >> 12;
        int m   = (r >> 7) & 31;
        int c   = r & 127;
        const float* W = (mat == 0) ? Wq : (mat == 1) ? Wk : Wv;
        const int dst = e * 12288 + mat * 4096 + m * 128 + (c ^ ((m & 7) << 3));
        wt_img[dst] = (short)f2bfu(W[((size_t)e * Cc + c) * Mc + m]);
    } else {
        for (int idx = t; idx < Mc * 32; idx += 256) {
            int m = idx >> 5, k = idx & 31;
            bankM[idx] = (short)f2bfu((k < MEMc) ? membank[k * Mc + m] : 0.f);
        }
        if (t < MEMc) {
            float g0 = 0.f, g1 = 0.f;
            for (int m = 0; m < Mc; ++m) {
                float b = membank[t * Mc + m];
                g0 = fmaf(iq[m], b, g0);
                g1 = fmaf(iq[Mc + m], b, g1);
            }
            G2[2 * t]     = g0;
            G2[2 * t + 1] = g1;
        }
    }
}

// ---- projection for one unit: q/k/v^T = W^T @ H^T (B-frags from swizzled sh_wt)
__device__ __forceinline__ void proj(const short* __restrict__ sh_wt, const bf16x8* a,
                                     int lo, int hi,
                                     f32x4 q_[2], f32x4 k_[2], f32x4 v_[2]) {
    #pragma unroll
    for (int nt = 0; nt < 2; ++nt)
        q_[nt] = k_[nt] = v_[nt] = (f32x4){0.f, 0.f, 0.f, 0.f};
    const int swz = (lo & 7) << 3;
    int col[4];
    #pragma unroll
    for (int kt = 0; kt < 4; ++kt) col[kt] = (kt * 32 + hi * 8) ^ swz;
    const short* wrow = sh_wt + lo * 128;
    #pragma unroll
    for (int nt = 0; nt < 2; ++nt) {
        const short* p0 = wrow + nt * 2048;
        #pragma unroll
        for (int kt = 0; kt < 4; ++kt) {
            const bf16x8 wq = *(const bf16x8*)(p0 + col[kt]);
            const bf16x8 wk = *(const bf16x8*)(p0 + 4096 + col[kt]);
            const bf16x8 wv = *(const bf16x8*)(p0 + 8192 + col[kt]);
            q_[nt] = __builtin_amdgcn_mfma_f32_16x16x32_bf16(wq, a[kt], q_[nt], 0, 0, 0);
            k_[nt] = __builtin_amdgcn_mfma_f32_16x16x32_bf16(wk, a[kt], k_[nt], 0, 0, 0);
            v_[nt] = __builtin_amdgcn_mfma_f32_16x16x32_bf16(wv, a[kt], v_[nt], 0, 0, 0);
        }
    }
}

// ---- mem-gate exps (packed bf16 pairs), unnormalized (1/l cancels in cosine)
__device__ __forceinline__ void gate_pd(const float* __restrict__ G2, float2 in2, unsigned pd[10]) {
    #pragma unroll
    for (int kp = 0; kp < 10; ++kp) {
        const float4 g = *(const float4*)(G2 + 4 * kp);
        pd[kp] = pk2bf(__expf(in2.x * g.x + in2.y * g.y),
                       __expf(in2.x * g.z + in2.y * g.w));
    }
}

// ---- memories^T = bank^T @ P2^T (reg-only bpermute B-frag); row group wu
__device__ __forceinline__ void mem_read(const short* __restrict__ bankM,
                                         const unsigned pd[10], int lo, int hi, int wu,
                                         f32x4 am[2]) {
    am[0] = am[1] = (f32x4){0.f, 0.f, 0.f, 0.f};
    const int addrD = (wu * 16 + lo) * 4;
    unsigned Wd[10];
    #pragma unroll
    for (int u = 0; u < 10; ++u)
        Wd[u] = __builtin_amdgcn_ds_bpermute(addrD, (int)pd[u]);
    unsigned b[4];
    #pragma unroll
    for (int u = 0; u < 4; ++u) {
        const unsigned l_ = (hi == 0) ? Wd[u] : Wd[4 + u];
        const unsigned h_ = (u < 2) ? ((hi == 2) ? Wd[8 + u] : 0u) : 0u;
        b[u] = (hi < 2) ? l_ : h_;
    }
    const bf16x8 bp2 = __builtin_bit_cast(bf16x8, (uint4){b[0], b[1], b[2], b[3]});
    #pragma unroll
    for (int nt = 0; nt < 2; ++nt) {
        const bf16x8 ab = *(const bf16x8*)(bankM + (nt * 16 + lo) * 32 + hi * 8);
        am[nt] = __builtin_amdgcn_mfma_f32_16x16x32_bf16(ab, bp2, am[nt], 0, 0, 0);
    }
}

// ---- E + F + cosine + store for one unit (this wave owns rows wu*16..wu*16+15)
__device__ __forceinline__ void attend_store(
    const short* __restrict__ shk, const short* __restrict__ shv,
    const unsigned q_pk[4], const f32x4 am[2],
    int lo, int hi, int wu, int A01, int A23, int addrA, int addrB,
    int bn, int e, float* __restrict__ out) {
    // E: energy^T = K @ Q^T; Q B-frag via bpermute; no max-subtraction
    unsigned pw[4][2];
    {
        unsigned l0 = __builtin_amdgcn_ds_bpermute(A01, (int)q_pk[0]);
        unsigned h0_ = __builtin_amdgcn_ds_bpermute(A01, (int)q_pk[2]);
        unsigned l1 = __builtin_amdgcn_ds_bpermute(A01, (int)q_pk[1]);
        unsigned h1_ = __builtin_amdgcn_ds_bpermute(A01, (int)q_pk[3]);
        unsigned l2 = __builtin_amdgcn_ds_bpermute(A23, (int)q_pk[0]);
        unsigned h2_ = __builtin_amdgcn_ds_bpermute(A23, (int)q_pk[2]);
        unsigned l3 = __builtin_amdgcn_ds_bpermute(A23, (int)q_pk[1]);
        unsigned h3_ = __builtin_amdgcn_ds_bpermute(A23, (int)q_pk[3]);
        const bf16x8 bq = __builtin_bit_cast(bf16x8, (uint4){
            (hi < 2) ? l0 : h0_, (hi < 2) ? l1 : h1_,
            (hi < 2) ? l2 : h2_, (hi < 2) ? l3 : h3_});
        #pragma unroll
        for (int st = 0; st < 4; ++st) {
            const bf16x8 akf = *(const bf16x8*)&shk[(st * 16 + lo) * LDK + hi * 8];
            const f32x4 en = __builtin_amdgcn_mfma_f32_16x16x32_bf16(
                akf, bq, (f32x4){0.f, 0.f, 0.f, 0.f}, 0, 0, 0);
            pw[st][0] = pk2bf(__expf(en[0]), __expf(en[1]));
            pw[st][1] = pk2bf(__expf(en[2]), __expf(en[3]));
        }
    }
    // F: att^T = V^T @ P^T; P B-frag from pw via bpermute
    f32x4 av[2];
    av[0] = av[1] = (f32x4){0.f, 0.f, 0.f, 0.f};
    {
        bf16x8 bp[2];
        #pragma unroll
        for (int kt = 0; kt < 2; ++kt) {
            unsigned wrd[4];
            #pragma unroll
            for (int uu = 0; uu < 4; ++uu) {
                const int adr = (uu < 2) ? addrA : addrB;
                const unsigned ev = __builtin_amdgcn_ds_bpermute(adr, (int)pw[2 * kt][uu & 1]);
                const unsigned od = __builtin_amdgcn_ds_bpermute(adr, (int)pw[2 * kt + 1][uu & 1]);
                wrd[uu] = (hi < 2) ? ev : od;
            }
            bp[kt] = __builtin_bit_cast(bf16x8, (uint4){wrd[0], wrd[1], wrd[2], wrd[3]});
        }
        #pragma unroll
        for (int nt = 0; nt < 2; ++nt)
            #pragma unroll
            for (int kt = 0; kt < 2; ++kt) {
                const bf16x8 avt = *(const bf16x8*)&shv[(nt * 16 + lo) * LDVT + kt * 32 + hi * 8];
                av[nt] = __builtin_amdgcn_mfma_f32_16x16x32_bf16(avt, bp[kt], av[nt], 0, 0, 0);
            }
    }
    // cosine vs in-register memories^T, store
    float d = 0.f, na = 0.f, nb = 0.f;
    #pragma unroll
    for (int nt = 0; nt < 2; ++nt)
        #pragma unroll
        for (int j = 0; j < 4; ++j) {
            const float av_ = av[nt][j], am_ = am[nt][j];
            d  = fmaf(av_, am_, d);
            na = fmaf(av_, av_, na);
            nb = fmaf(am_, am_, nb);
        }
    d  += __shfl_xor(d, 16);  d  += __shfl_xor(d, 32);
    na += __shfl_xor(na, 16); na += __shfl_xor(na, 32);
    nb += __shfl_xor(nb, 16); nb += __shfl_xor(nb, 32);
    if (hi == 0) {
        const float denom = fmaxf(sqrtf(na), 1e-8f) * fmaxf(sqrtf(nb), 1e-8f);
        out[((size_t)bn * Tc + wu * 16 + lo) * Ec + e] = d / denom;
    }
}

// 512-thread blocks, 8 waves = 2 units processed in PARALLEL (4 waves each).
// 24 waves/CU (3 blocks x 44 KB LDS), 1 barrier per unit.
__global__ __launch_bounds__(512, 6) void mg_mfma(
    const float* __restrict__ input,    // [B,N,T,2]
    const float* __restrict__ hidden,   // [E,B,N,T,C]
    const short* __restrict__ wt_img,   // [E][3][32][128] bf16, row-swizzled
    const short* __restrict__ bankM,    // [32][32] bf16 (memory^T, K zero-padded)
    const float* __restrict__ G2,       // [20][2] fp32
    float* __restrict__ out)            // [B,N,T,1,E]
{
    __shared__ __align__(16) short sh_wt[12288];          // 24576 B (shared by both units)
    __shared__ __align__(16) short sh_k [2][Tc * LDK];    // 2 x 5120 B
    __shared__ __align__(16) short sh_vt[2][Mc * LDVT];   // 2 x 4608 B -> 44032 B total

    const int t    = threadIdx.x;
    const int w    = t >> 6;          // 0..7
    const int u    = w >> 2;          // unit 0/1
    const int wu   = w & 3;           // wave-in-unit: owns rows wu*16..wu*16+15
    const int lane = t & 63;
    const int lo   = lane & 15;
    const int hi   = lane >> 4;
    const int e    = blockIdx.x >> 11;            // 8192 blocks: 2048 per expert
    const int bn   = (blockIdx.x & 2047) * 2 + u; // this wave's unit

    const int A01   = (((hi & 1) * 32) + lo) << 2;
    const int A23   = A01 + 64;
    const int addrA = (((hi & 1) * 2 + 0) * 16 + lo) * 4;
    const int addrB = (((hi & 1) * 2 + 1) * 16 + lo) * 4;

    // ---- A0: weight-slice DMA to LDS (512 threads x 16 B x 3 rounds = 24576 B)
    {
        const short* gsrc = wt_img + (size_t)e * 12288 + w * 512 + lane * 8;
        short* ldst = sh_wt + w * 512;
        #pragma unroll
        for (int c = 0; c < 3; ++c)
            gload_lds16(gsrc + c * 4096, ldst + c * 4096);
    }

    // ---- A1: this unit's hidden rows + gate input
    const float2 in2 = *(const float2*)(input + ((size_t)bn * Tc + lane) * 2);
    float4 h[8];
    {
        const float* hr = hidden + (((size_t)(e * 4096 + bn)) * Tc + wu * 16 + lo) * Cc + hi * 8;
        #pragma unroll
        for (int kt = 0; kt < 4; ++kt) {
            h[2 * kt]     = *(const float4*)(hr + kt * 32);
            h[2 * kt + 1] = *(const float4*)(hr + kt * 32 + 4);
        }
    }

    // ---- B + D in the load shadow (reg-only; no barrier dependence)
    f32x4 am[2];
    {
        unsigned pd[10];
        gate_pd(G2, in2, pd);
        mem_read(bankM, pd, lo, hi, wu, am);
    }

    // ---- convert A-frags (drains hidden loads)
    bf16x8 a[4];
    #pragma unroll
    for (int kt = 0; kt < 4; ++kt) {
        const float4 x = h[2 * kt], y = h[2 * kt + 1];
        a[kt] = __builtin_bit_cast(bf16x8, (uint4){pk2bf(x.x, x.y), pk2bf(x.z, x.w),
                                                   pk2bf(y.x, y.y), pk2bf(y.z, y.w)});
    }

    __syncthreads();   // #1: sh_wt visible (drains weight DMA)

    // ---- C: projections, write this unit's K/V to its LDS buffers, pack Q
    unsigned q_pk[4];
    {
        f32x4 q_[2], k_[2], v_[2];
        proj(sh_wt, a, lo, hi, q_, k_, v_);
        #pragma unroll
        for (int nt = 0; nt < 2; ++nt) {
            *(uint2*)&sh_k[u][(wu * 16 + lo) * LDK + nt * 16 + hi * 4] =
                (uint2){pk2bf(k_[nt][0], k_[nt][1]), pk2bf(k_[nt][2], k_[nt][3])};
            #pragma unroll
            for (int j = 0; j < 4; ++j)
                sh_vt[u][(nt * 16 + hi * 4 + j) * LDVT + wu * 16 + lo] = (short)f2bfu(v_[nt][j]);
            q_pk[nt * 2]     = pk2bf(q_[nt][0], q_[nt][1]);
            q_pk[nt * 2 + 1] = pk2bf(q_[nt][2], q_[nt][3]);
        }
    }

    __syncthreads();   // #2: both units' K/V ready

    // ---- E + F + cosine + store
    attend_store(sh_k[u], sh_vt[u], q_pk, am, lo, hi, wu, A01, A23, addrA, addrB, bn, e, out);
}

extern "C" void kernel_launch(void* const* d_in, const int* in_sizes, int n_in,
                              void* d_out, int out_size, void* d_ws, size_t ws_size,
                              hipStream_t stream) {
    const float* input   = (const float*)d_in[0];
    const float* hidden  = (const float*)d_in[1];
    const float* membank = (const float*)d_in[2];
    const float* iq      = (const float*)d_in[3];
    const float* Wq      = (const float*)d_in[4];
    const float* Wk      = (const float*)d_in[5];
    const float* Wv      = (const float*)d_in[6];
    float* out = (float*)d_out;

    short* wt_img = (short*)d_ws;                      // 98304 B
    short* bankM  = (short*)((char*)d_ws + 98304);     //  2048 B
    float* G2     = (float*)((char*)d_ws + 100352);    //   160 B

    prep<<<193, 256, 0, stream>>>(Wq, Wk, Wv, membank, iq, wt_img, bankM, G2);
    mg_mfma<<<Ec * Bc * Nc / 2, 512, 0, stream>>>(input, hidden, wt_img, bankM, G2, out);
}